// Round 5
// baseline (405.714 us; speedup 1.0000x reference)
//
#include <hip/hip_runtime.h>

#define BB 2
#define NN 1024
#define MM 1024
#define SS 4
#define DMODEL 512
#define HH 8
#define CC 64
// scale = 1/sqrt(64) = 0.125; LOG2E folded into qs scales

typedef __attribute__((ext_vector_type(8))) short short8;
typedef __attribute__((ext_vector_type(4))) short short4v;
typedef __attribute__((ext_vector_type(4))) float f32x4;

__device__ __forceinline__ unsigned short f2bf(float x) {   // truncation (lo-part captures residual)
    union { float f; unsigned u; } c; c.f = x;
    return (unsigned short)(c.u >> 16);
}
__device__ __forceinline__ float bf2f(unsigned short h) {
    union { float f; unsigned u; } c; c.u = ((unsigned)h) << 16;
    return c.f;
}
__device__ __forceinline__ float fexp2(float x) { return __builtin_amdgcn_exp2f(x); }

#define MFMA16(a, b, c) __builtin_amdgcn_mfma_f32_16x16x32_bf16(a, b, c, 0, 0, 0)

__device__ __forceinline__ void gll16(const void* g, void* l) {
    __builtin_amdgcn_global_load_lds((const __attribute__((address_space(1))) void*)g,
                                     (__attribute__((address_space(3))) void*)l, 16, 0, 0);
}
// streaming (non-temporal) stores: out_attn/out_hidden are write-once, never
// re-read on device -> write around L2/L3 so K/V staging stays cache-resident
__device__ __forceinline__ void nt_store4(float* p, f32x4 v) {
    __builtin_nontemporal_store(v, (f32x4*)p);
}
__device__ __forceinline__ void nt_store1(float* p, float v) {
    __builtin_nontemporal_store(v, p);
}

// ---------------------------------------------------------------------------
// Kernel 1: projections  y = x @ W^T + bias, via split-bf16 MFMA (3 terms:
// Xh·Wh + Xl·Wh + Xh·Wl).  Same XOR-swizzled fragment layout as attn phase B.
//   z=0: q -> fp32 (b,h,n,c)
//   z=1: k -> split bf16 hi/lo, [bh][m][8 chunks of 8], chunk ^= (m&7)
//   z=2: v -> transposed bf16 [bh][c][mtile], m-chunk ^= (c&7)  (LDS bounce)
// ---------------------------------------------------------------------------
__global__ __launch_bounds__(256) void proj_kernel(
    const float* __restrict__ xq, const float* __restrict__ xk, const float* __restrict__ xv,
    const float* __restrict__ Wq, const float* __restrict__ Wk, const float* __restrict__ Wv,
    const float* __restrict__ bq, const float* __restrict__ bk, const float* __restrict__ bv,
    float* __restrict__ qout, unsigned short* __restrict__ khi,
    unsigned short* __restrict__ klo, unsigned short* __restrict__ vTg)
{
    __shared__ __align__(16) unsigned short s_xh[64 * 64];
    __shared__ __align__(16) unsigned short s_xl[64 * 64];
    __shared__ __align__(16) unsigned short s_wh[64 * 64];
    __shared__ __align__(16) unsigned short s_wl[64 * 64];

    const int z = blockIdx.z;
    const float* x    = (z == 0) ? xq : (z == 1) ? xk : xv;
    const float* W    = (z == 0) ? Wq : (z == 1) ? Wk : Wv;
    const float* bias = (z == 0) ? bq : (z == 1) ? bk : bv;

    const int t    = threadIdx.x;
    const int lane = t & 63;
    const int w    = t >> 6;
    const int l15  = lane & 15;
    const int quad = lane >> 4;
    const int r0   = blockIdx.y * 64;       // row tile (flattened b*n / b*m)
    const int o0   = blockIdx.x * 64;       // output-col tile (= head h*64)

    f32x4 acc[4];
    #pragma unroll
    for (int i = 0; i < 4; ++i) acc[i] = (f32x4){0.f, 0.f, 0.f, 0.f};

    const int srow = t >> 4, sc4 = t & 15;  // staging: thread -> (row, 4-float col)

    #pragma unroll 1
    for (int kt = 0; kt < 8; ++kt) {
        const int k0 = kt * 64;
        __syncthreads();                     // previous iter's frag reads done
        #pragma unroll
        for (int i = 0; i < 4; ++i) {
            const int row = srow + i * 16;
            const int pos = (row << 6) + ((((sc4 >> 1) ^ (row & 7)) << 3) + ((sc4 & 1) << 2));
            {
                const float4 v = *(const float4*)&x[(size_t)(r0 + row) * DMODEL + k0 + sc4 * 4];
                const unsigned short h0 = f2bf(v.x), h1 = f2bf(v.y), h2 = f2bf(v.z), h3 = f2bf(v.w);
                short4v hh = { (short)h0, (short)h1, (short)h2, (short)h3 };
                short4v ll = { (short)f2bf(v.x - bf2f(h0)), (short)f2bf(v.y - bf2f(h1)),
                               (short)f2bf(v.z - bf2f(h2)), (short)f2bf(v.w - bf2f(h3)) };
                *(short4v*)&s_xh[pos] = hh;
                *(short4v*)&s_xl[pos] = ll;
            }
            {
                const float4 v = *(const float4*)&W[(size_t)(o0 + row) * DMODEL + k0 + sc4 * 4];
                const unsigned short h0 = f2bf(v.x), h1 = f2bf(v.y), h2 = f2bf(v.z), h3 = f2bf(v.w);
                short4v hh = { (short)h0, (short)h1, (short)h2, (short)h3 };
                short4v ll = { (short)f2bf(v.x - bf2f(h0)), (short)f2bf(v.y - bf2f(h1)),
                               (short)f2bf(v.z - bf2f(h2)), (short)f2bf(v.w - bf2f(h3)) };
                *(short4v*)&s_wh[pos] = hh;
                *(short4v*)&s_wl[pos] = ll;
            }
        }
        __syncthreads();

        const int arow = (w << 4) + l15;
        const int asw  = arow & 7;
        const short8 ah0 = *(const short8*)&s_xh[(arow << 6) + ((quad ^ asw) << 3)];
        const short8 ah1 = *(const short8*)&s_xh[(arow << 6) + (((4 | quad) ^ asw) << 3)];
        const short8 al0 = *(const short8*)&s_xl[(arow << 6) + ((quad ^ asw) << 3)];
        const short8 al1 = *(const short8*)&s_xl[(arow << 6) + (((4 | quad) ^ asw) << 3)];
        #pragma unroll
        for (int ct = 0; ct < 4; ++ct) {
            const int brow = (ct << 4) + l15;
            const int bsw  = brow & 7;
            const short8 bh0 = *(const short8*)&s_wh[(brow << 6) + ((quad ^ bsw) << 3)];
            const short8 bh1 = *(const short8*)&s_wh[(brow << 6) + (((4 | quad) ^ bsw) << 3)];
            const short8 bl0 = *(const short8*)&s_wl[(brow << 6) + ((quad ^ bsw) << 3)];
            const short8 bl1 = *(const short8*)&s_wl[(brow << 6) + (((4 | quad) ^ bsw) << 3)];
            acc[ct] = MFMA16(ah0, bh0, acc[ct]);
            acc[ct] = MFMA16(ah1, bh1, acc[ct]);
            acc[ct] = MFMA16(al0, bh0, acc[ct]);
            acc[ct] = MFMA16(al1, bh1, acc[ct]);
            acc[ct] = MFMA16(ah0, bl0, acc[ct]);
            acc[ct] = MFMA16(ah1, bl1, acc[ct]);
        }
    }

    // ---- epilogue: C/D col = lane&15, row = quad*4+r (within wave's 16 rows)
    const int h = o0 >> 6;
    if (z == 0) {
        #pragma unroll
        for (int r = 0; r < 4; ++r) {
            const int rg = r0 + (w << 4) + (quad << 2) + r;
            const int bb = rg >> 10, n = rg & 1023;
            float* orow = qout + ((size_t)(bb * HH + h) * NN + n) * CC;
            #pragma unroll
            for (int ct = 0; ct < 4; ++ct)
                orow[(ct << 4) + l15] = acc[ct][r] + bias[o0 + (ct << 4) + l15];
        }
    } else if (z == 1) {
        #pragma unroll
        for (int r = 0; r < 4; ++r) {
            const int rg = r0 + (w << 4) + (quad << 2) + r;
            const int bb = rg >> 10, m = rg & 1023;
            const size_t base = ((size_t)(bb * HH + h) << 16) + ((size_t)m << 6);
            const int msw = m & 7;
            #pragma unroll
            for (int ct = 0; ct < 4; ++ct) {
                const int c = (ct << 4) + l15;
                const float o = acc[ct][r] + bias[o0 + c];
                const unsigned short hh = f2bf(o);
                const unsigned short ll = f2bf(o - bf2f(hh));
                const size_t addr = base + ((((c >> 3) ^ msw) << 3) + (c & 7));
                khi[addr] = hh;
                klo[addr] = ll;
            }
        }
    } else {
        __syncthreads();                     // all frag reads done before bounce reuse
        unsigned short* s_t = s_xh;          // [c=64][64] mirrored vT tile (swizzled)
        #pragma unroll
        for (int r = 0; r < 4; ++r) {
            const int m_l = (w << 4) + (quad << 2) + r;
            #pragma unroll
            for (int ct = 0; ct < 4; ++ct) {
                const int c = (ct << 4) + l15;
                const float o = acc[ct][r] + bias[o0 + c];
                s_t[(c << 6) + ((((m_l >> 3) ^ (c & 7)) << 3) + (m_l & 7))] = f2bf(o);
            }
        }
        __syncthreads();
        const int bb = r0 >> 10, m0 = r0 & 1023;
        const size_t bhb = ((size_t)(bb * HH + h) << 16);
        const int c = t >> 2, part = t & 3;
        const short8 v0 = *(const short8*)&s_t[(c << 6) + (part << 4)];
        const short8 v1 = *(const short8*)&s_t[(c << 6) + (part << 4) + 8];
        unsigned short* dst = vTg + bhb + ((size_t)c << 10) + m0 + (part << 4);
        *(short8*)&dst[0] = v0;
        *(short8*)&dst[8] = v1;
    }
}

// ---------------------------------------------------------------------------
// Kernel 2: fused subspace attention, MFMA bf16.
// R4 deltas (one theory: stop K/V HBM re-fetch):
//   (a) out_attn/out_hidden stores -> non-temporal (write around L2/L3; these
//       are never re-read on device, and their 285 MB stream was evicting the
//       K/V staging working set).
//   (b) bh-major block swizzle: blk = ntile*16 + bh  =>  blk%8 = bh%8, so all
//       128 blocks of a bh land on one XCD; its 384 KB K/V is fetched once
//       and stays L2-resident (2 bh x 384 KB << 4 MB/XCD).
// ---------------------------------------------------------------------------
__global__ __launch_bounds__(256, 3) void attn_kernel(
    const float* __restrict__ qws,
    const unsigned short* __restrict__ khi_g, const unsigned short* __restrict__ klo_g,
    const unsigned short* __restrict__ vT_g,
    const float* __restrict__ qsub, const float* __restrict__ ksub,
    float* __restrict__ out_hidden, float* __restrict__ out_attn)
{
    // smem layout (50048 B total, aliased regions):
    //   [0,16384)      region0: B: kh[64][64]+kl[64][64]; C: vT[64][64]+stash[32][72]
    //   [16384,49280)  region1: s_S [8][1028] fp32; phase-A qh/ql live here first
    //   [49280,49536)  s_qs, s_inv
    __shared__ __align__(16) unsigned char smem[50048];
    unsigned short* s_kh = (unsigned short*)smem;
    unsigned short* s_kl = s_kh + 4096;
    unsigned short* s_vT = s_kh;            // phase C alias
    unsigned short* s_at = s_kh + 4096;     // phase C stash [32][72]
    float* s_S  = (float*)(smem + 16384);   // stride 1028 floats
    unsigned short* s_qh = (unsigned short*)(smem + 16384);
    unsigned short* s_ql = s_qh + 16 * 72;
    float* s_qs  = (float*)(smem + 49280);  // qsub * 0.125 * log2e, [s][n]
    float* s_inv = (float*)(smem + 49408);  // -log2(denom), [s][n]

    const int t     = threadIdx.x;
    const int blk   = blockIdx.x;           // 2048 = ntile*16 + bh  (bh-major swizzle)
    const int bh    = blk & 15;
    const int ntile = blk >> 4;
    const int b     = bh >> 3;
    const int h     = bh & 7;
    const int n0    = ntile * 8;

    const int lane = t & 63;
    const int w    = t >> 6;                // wave 0..3
    const int l15  = lane & 15;
    const int quad = lane >> 4;

    // ---- Phase A: q tile -> split bf16 LDS; qs scales ----
    if (t < 128) {
        const int row = t >> 4, c4 = t & 15;
        const float4 qv = *(const float4*)&qws[((size_t)bh * NN + n0 + row) * CC + c4 * 4];
        const unsigned short h0 = f2bf(qv.x), h1 = f2bf(qv.y), h2 = f2bf(qv.z), h3 = f2bf(qv.w);
        short4v hh = { (short)h0, (short)h1, (short)h2, (short)h3 };
        short4v ll = { (short)f2bf(qv.x - bf2f(h0)), (short)f2bf(qv.y - bf2f(h1)),
                       (short)f2bf(qv.z - bf2f(h2)), (short)f2bf(qv.w - bf2f(h3)) };
        *(short4v*)&s_qh[row * 72 + c4 * 4] = hh;
        *(short4v*)&s_ql[row * 72 + c4 * 4] = ll;
    }
    for (int i = 576 + t; i < 1152; i += 256) { s_qh[i] = 0; s_ql[i] = 0; }   // zero pad rows 8..15
    if (t < 32) s_qs[t] = qsub[((size_t)b * SS + (t >> 3)) * NN + n0 + (t & 7)]
                        * (0.125f * 1.44269504088896f);
    __syncthreads();

    // per-wave q fragments (A-layout: row = lane&15, k = quad*8+j), reused all m-tiles.
    const short8 qh0 = *(const short8*)&s_qh[l15 * 72 + 0  + quad * 8];
    const short8 qh1 = *(const short8*)&s_qh[l15 * 72 + 32 + quad * 8];
    const short8 ql0 = *(const short8*)&s_ql[l15 * 72 + 0  + quad * 8];
    const short8 ql1 = *(const short8*)&s_ql[l15 * 72 + 32 + quad * 8];

    const unsigned short* kh_g = khi_g + ((size_t)bh << 16);
    const unsigned short* kl_g = klo_g + ((size_t)bh << 16);

    // ---- Phase B: S = q@k^T (split bf16), S->LDS fp32 ----
    #pragma unroll 1
    for (int mt = 0; mt < 16; ++mt) {
        const int m0 = mt << 6;
        #pragma unroll
        for (int i = 0; i < 4; ++i) {           // stage 16 KB (khi+klo tile) via gll width-16
            const int idx = w * 4 + i;          // 0..15
            const int j   = ((idx & 7) << 6) + lane;           // chunk id within 8 KB half
            const unsigned short* src = ((idx < 8) ? kh_g : kl_g)
                                      + ((size_t)(m0 + (j >> 3)) << 6) + ((j & 7) << 3);
            gll16(src, s_kh + (idx << 9));
        }
        __syncthreads();                         // drains gll (vmcnt0); no stores in flight in B

        const int krow = (w << 4) + l15;
        const int sw   = krow & 7;
        const short8 kh0f = *(const short8*)&s_kh[(krow << 6) + ((quad ^ sw) << 3)];
        const short8 kh1f = *(const short8*)&s_kh[(krow << 6) + (((4 | quad) ^ sw) << 3)];
        const short8 kl0f = *(const short8*)&s_kl[(krow << 6) + ((quad ^ sw) << 3)];
        const short8 kl1f = *(const short8*)&s_kl[(krow << 6) + (((4 | quad) ^ sw) << 3)];
        f32x4 acc = {0.f, 0.f, 0.f, 0.f};
        acc = MFMA16(qh0, kh0f, acc);
        acc = MFMA16(qh1, kh1f, acc);
        acc = MFMA16(ql0, kh0f, acc);
        acc = MFMA16(ql1, kh1f, acc);
        acc = MFMA16(qh0, kl0f, acc);
        acc = MFMA16(qh1, kl1f, acc);

        if (quad < 2) {                          // C/D: col=lane&15 (m), row=quad*4+r (n)
            const int mglob = m0 + krow;
            #pragma unroll
            for (int r = 0; r < 4; ++r)
                s_S[(quad * 4 + r) * 1028 + mglob] = acc[r];
        }
        __syncthreads();
    }

    // ---- Phase C setup + pre-issue tile-0 V staging (covered by the sweep) ----
    const unsigned short* vg = vT_g + ((size_t)bh << 16);
    auto stage_v = [&](int m0v) {
        #pragma unroll
        for (int i = 0; i < 2; ++i) {
            const int idx = (w << 1) + i;        // 0..7
            const int j   = (idx << 6) + lane;
            const unsigned short* src = vg + ((size_t)(j >> 3) << 10) + m0v + ((j & 7) << 3);
            gll16(src, s_vT + (idx << 9));
        }
    };
    stage_v(0);

    // ---- denominator sweep: all 256 lanes, bank-rotated s_S reads ----
    {
        const int sn = t >> 3, mg = t & 7;
        const int sD = sn >> 3, nD = sn & 7;
        const float qsD = s_qs[sn];
        const float* ksD  = ksub + ((size_t)b * SS + sD) * MM + (mg << 7);
        const float* Srow = s_S + nD * 1028 + (mg << 7);
        float d = 0.f;
        #pragma unroll 4
        for (int ii = 0; ii < 32; ++ii) {
            const int i = (ii + mg) & 31;        // rotate start: spreads banks across mg
            const f32x4  Sv = *(const f32x4*)&Srow[i << 2];
            const float4 kv = *(const float4*)&ksD[i << 2];
            d += fexp2(Sv[0] * qsD * kv.x) + fexp2(Sv[1] * qsD * kv.y)
               + fexp2(Sv[2] * qsD * kv.z) + fexp2(Sv[3] * qsD * kv.w);
        }
        d += __shfl_xor(d, 1); d += __shfl_xor(d, 2); d += __shfl_xor(d, 4);
        if (mg == 0) s_inv[sn] = -__builtin_amdgcn_logf(d);   // -log2(denom)
    }
    __syncthreads();                             // publishes s_inv; drains tile-0 gll

    // ---- Phase C: exp + attn store + stash; AV via MFMA ----
    const int sn = t >> 3, mg = t & 7;
    const int sC = sn >> 3, nC = sn & 7;
    const float linvC = s_inv[sn];
    const float qsC   = s_qs[sn];
    const float* ksC = ksub + ((size_t)b * SS + sC) * MM;
    float* attnC = out_attn + (((size_t)(bh * SS + sC)) * NN + n0 + nC) * MM;
    const int Mt = w >> 1, nsel = w & 1;
    f32x4 av0 = {0.f, 0.f, 0.f, 0.f}, av1 = {0.f, 0.f, 0.f, 0.f};

    #pragma unroll 1
    for (int mt = 0; mt < 16; ++mt) {
        const int m0 = mt << 6;
        {   // exp2(arg - log2(denom)): fp32 nt global store + bf16 stash
            const f32x4 S0 = *(const f32x4*)&s_S[nC * 1028 + m0 + (mg << 3)];
            const f32x4 S1 = *(const f32x4*)&s_S[nC * 1028 + m0 + (mg << 3) + 4];
            const float4 k0 = *(const float4*)&ksC[m0 + (mg << 3)];
            const float4 k1 = *(const float4*)&ksC[m0 + (mg << 3) + 4];
            f32x4 e0, e1;
            e0[0] = fexp2(fmaf(S0[0] * qsC, k0.x, linvC));
            e0[1] = fexp2(fmaf(S0[1] * qsC, k0.y, linvC));
            e0[2] = fexp2(fmaf(S0[2] * qsC, k0.z, linvC));
            e0[3] = fexp2(fmaf(S0[3] * qsC, k0.w, linvC));
            e1[0] = fexp2(fmaf(S1[0] * qsC, k1.x, linvC));
            e1[1] = fexp2(fmaf(S1[1] * qsC, k1.y, linvC));
            e1[2] = fexp2(fmaf(S1[2] * qsC, k1.z, linvC));
            e1[3] = fexp2(fmaf(S1[3] * qsC, k1.w, linvC));
            nt_store4(&attnC[m0 + (mg << 3)],     e0);
            nt_store4(&attnC[m0 + (mg << 3) + 4], e1);
            short8 pk = { (short)f2bf(e0[0]), (short)f2bf(e0[1]), (short)f2bf(e0[2]), (short)f2bf(e0[3]),
                          (short)f2bf(e1[0]), (short)f2bf(e1[1]), (short)f2bf(e1[2]), (short)f2bf(e1[3]) };
            *(short8*)&s_at[sn * 72 + (mg << 3)] = pk;
        }
        // counted wait: 2 glls (oldest) must retire; the 2 attn stores stay in flight
        asm volatile("s_waitcnt vmcnt(2) lgkmcnt(0)" ::: "memory");
        __builtin_amdgcn_sched_barrier(0);
        __builtin_amdgcn_s_barrier();
        __builtin_amdgcn_sched_barrier(0);

        // AV: D[32 sn][64 c] over K=64 this tile; wave: M-tile Mt, N-tiles {nsel, nsel+2}
        #pragma unroll
        for (int Ks = 0; Ks < 2; ++Ks) {
            const int c0r = (nsel << 4) + l15, c1r = ((nsel + 2) << 4) + l15;
            const int swv = l15 & 7;
            const short8 a   = *(const short8*)&s_at[((Mt << 4) + l15) * 72 + (Ks << 5) + (quad << 3)];
            const short8 vb0 = *(const short8*)&s_vT[(c0r << 6) + ((((Ks << 2) | quad) ^ swv) << 3)];
            const short8 vb1 = *(const short8*)&s_vT[(c1r << 6) + ((((Ks << 2) | quad) ^ swv) << 3)];
            av0 = MFMA16(a, vb0, av0);
            av1 = MFMA16(a, vb1, av1);
        }
        asm volatile("s_waitcnt lgkmcnt(0)" ::: "memory");
        __builtin_amdgcn_sched_barrier(0);
        __builtin_amdgcn_s_barrier();
        __builtin_amdgcn_sched_barrier(0);
        if (mt < 15) stage_v(m0 + 64);           // next tile; pinned after barrier
        __builtin_amdgcn_sched_barrier(0);
    }

    // ---- hidden store: lane holds rows Mt*16+quad*4+r, cols Nt*16+l15 ----
    #pragma unroll
    for (int r = 0; r < 4; ++r) {
        const int snr = Mt * 16 + quad * 4 + r;
        const int s = snr >> 3, n = snr & 7;
        float* orow = out_hidden + (((size_t)b * SS + s) * NN + n0 + n) * DMODEL + h * CC;
        nt_store1(&orow[nsel * 16 + l15],        av0[r]);
        nt_store1(&orow[(nsel + 2) * 16 + l15],  av1[r]);
    }
}

extern "C" void kernel_launch(void* const* d_in, const int* in_sizes, int n_in,
                              void* d_out, int out_size, void* d_ws, size_t ws_size,
                              hipStream_t stream) {
    const float* xq   = (const float*)d_in[0];
    const float* xk   = (const float*)d_in[1];
    const float* xv   = (const float*)d_in[2];
    const float* qsub = (const float*)d_in[3];
    const float* ksub = (const float*)d_in[4];
    const float* Wq   = (const float*)d_in[5];
    const float* bq   = (const float*)d_in[6];
    const float* Wk   = (const float*)d_in[7];
    const float* bk   = (const float*)d_in[8];
    const float* Wv   = (const float*)d_in[9];
    const float* bv   = (const float*)d_in[10];

    float* ws = (float*)d_ws;
    // ws layout: q fp32 (4 MB) | khi bf16 (2 MB) | klo bf16 (2 MB) | vT bf16 (2 MB)
    float* qf = ws;
    unsigned short* khi = (unsigned short*)(ws + 1048576);
    unsigned short* klo = khi + 1048576;
    unsigned short* vTg = klo + 1048576;

    float* out_hidden = (float*)d_out;              // (B,S,N,512)
    float* out_attn   = out_hidden + (size_t)BB * SS * NN * DMODEL;  // (B,H,S,N,M)

    proj_kernel<<<dim3(8, 32, 3), 256, 0, stream>>>(xq, xk, xv, Wq, Wk, Wv, bq, bk, bv,
                                                    qf, khi, klo, vTg);
    attn_kernel<<<dim3(2048), 256, 0, stream>>>(qf, khi, klo, vTg,
                                                qsub, ksub, out_hidden, out_attn);
}

// Round 7
// 372.934 us; speedup vs baseline: 1.0879x; 1.0879x over previous
//
#include <hip/hip_runtime.h>

#define BB 2
#define NN 1024
#define MM 1024
#define SS 4
#define DMODEL 512
#define HH 8
#define CC 64
// scale = 1/sqrt(64) = 0.125; LOG2E folded into qs scales

typedef __attribute__((ext_vector_type(8))) short short8;
typedef __attribute__((ext_vector_type(4))) short short4v;
typedef __attribute__((ext_vector_type(4))) float f32x4;

__device__ __forceinline__ unsigned short f2bf(float x) {   // truncation (lo-part captures residual)
    union { float f; unsigned u; } c; c.f = x;
    return (unsigned short)(c.u >> 16);
}
__device__ __forceinline__ float bf2f(unsigned short h) {
    union { float f; unsigned u; } c; c.u = ((unsigned)h) << 16;
    return c.f;
}
__device__ __forceinline__ float fexp2(float x) { return __builtin_amdgcn_exp2f(x); }

#define MFMA16(a, b, c) __builtin_amdgcn_mfma_f32_16x16x32_bf16(a, b, c, 0, 0, 0)

__device__ __forceinline__ void gll16(const void* g, void* l) {
    __builtin_amdgcn_global_load_lds((const __attribute__((address_space(1))) void*)g,
                                     (__attribute__((address_space(3))) void*)l, 16, 0, 0);
}

// ---------------------------------------------------------------------------
// Kernel 1: projections  y = x @ W^T + bias, via split-bf16 MFMA (3 terms:
// Xh·Wh + Xl·Wh + Xh·Wl).  Same XOR-swizzled fragment layout as attn phase B.
//   z=0: q -> fp32 (b,h,n,c)
//   z=1: k -> split bf16 hi/lo, [bh][m][8 chunks of 8], chunk ^= (m&7)
//   z=2: v -> transposed bf16 [bh][c][mtile], m-chunk ^= (c&7)  (LDS bounce)
// ---------------------------------------------------------------------------
__global__ __launch_bounds__(256) void proj_kernel(
    const float* __restrict__ xq, const float* __restrict__ xk, const float* __restrict__ xv,
    const float* __restrict__ Wq, const float* __restrict__ Wk, const float* __restrict__ Wv,
    const float* __restrict__ bq, const float* __restrict__ bk, const float* __restrict__ bv,
    float* __restrict__ qout, unsigned short* __restrict__ khi,
    unsigned short* __restrict__ klo, unsigned short* __restrict__ vTg)
{
    __shared__ __align__(16) unsigned short s_xh[64 * 64];
    __shared__ __align__(16) unsigned short s_xl[64 * 64];
    __shared__ __align__(16) unsigned short s_wh[64 * 64];
    __shared__ __align__(16) unsigned short s_wl[64 * 64];

    const int z = blockIdx.z;
    const float* x    = (z == 0) ? xq : (z == 1) ? xk : xv;
    const float* W    = (z == 0) ? Wq : (z == 1) ? Wk : Wv;
    const float* bias = (z == 0) ? bq : (z == 1) ? bk : bv;

    const int t    = threadIdx.x;
    const int lane = t & 63;
    const int w    = t >> 6;
    const int l15  = lane & 15;
    const int quad = lane >> 4;
    const int r0   = blockIdx.y * 64;       // row tile (flattened b*n / b*m)
    const int o0   = blockIdx.x * 64;       // output-col tile (= head h*64)

    f32x4 acc[4];
    #pragma unroll
    for (int i = 0; i < 4; ++i) acc[i] = (f32x4){0.f, 0.f, 0.f, 0.f};

    const int srow = t >> 4, sc4 = t & 15;  // staging: thread -> (row, 4-float col)

    #pragma unroll 1
    for (int kt = 0; kt < 8; ++kt) {
        const int k0 = kt * 64;
        __syncthreads();                     // previous iter's frag reads done
        #pragma unroll
        for (int i = 0; i < 4; ++i) {
            const int row = srow + i * 16;
            const int pos = (row << 6) + ((((sc4 >> 1) ^ (row & 7)) << 3) + ((sc4 & 1) << 2));
            {
                const float4 v = *(const float4*)&x[(size_t)(r0 + row) * DMODEL + k0 + sc4 * 4];
                const unsigned short h0 = f2bf(v.x), h1 = f2bf(v.y), h2 = f2bf(v.z), h3 = f2bf(v.w);
                short4v hh = { (short)h0, (short)h1, (short)h2, (short)h3 };
                short4v ll = { (short)f2bf(v.x - bf2f(h0)), (short)f2bf(v.y - bf2f(h1)),
                               (short)f2bf(v.z - bf2f(h2)), (short)f2bf(v.w - bf2f(h3)) };
                *(short4v*)&s_xh[pos] = hh;
                *(short4v*)&s_xl[pos] = ll;
            }
            {
                const float4 v = *(const float4*)&W[(size_t)(o0 + row) * DMODEL + k0 + sc4 * 4];
                const unsigned short h0 = f2bf(v.x), h1 = f2bf(v.y), h2 = f2bf(v.z), h3 = f2bf(v.w);
                short4v hh = { (short)h0, (short)h1, (short)h2, (short)h3 };
                short4v ll = { (short)f2bf(v.x - bf2f(h0)), (short)f2bf(v.y - bf2f(h1)),
                               (short)f2bf(v.z - bf2f(h2)), (short)f2bf(v.w - bf2f(h3)) };
                *(short4v*)&s_wh[pos] = hh;
                *(short4v*)&s_wl[pos] = ll;
            }
        }
        __syncthreads();

        const int arow = (w << 4) + l15;
        const int asw  = arow & 7;
        const short8 ah0 = *(const short8*)&s_xh[(arow << 6) + ((quad ^ asw) << 3)];
        const short8 ah1 = *(const short8*)&s_xh[(arow << 6) + (((4 | quad) ^ asw) << 3)];
        const short8 al0 = *(const short8*)&s_xl[(arow << 6) + ((quad ^ asw) << 3)];
        const short8 al1 = *(const short8*)&s_xl[(arow << 6) + (((4 | quad) ^ asw) << 3)];
        #pragma unroll
        for (int ct = 0; ct < 4; ++ct) {
            const int brow = (ct << 4) + l15;
            const int bsw  = brow & 7;
            const short8 bh0 = *(const short8*)&s_wh[(brow << 6) + ((quad ^ bsw) << 3)];
            const short8 bh1 = *(const short8*)&s_wh[(brow << 6) + (((4 | quad) ^ bsw) << 3)];
            const short8 bl0 = *(const short8*)&s_wl[(brow << 6) + ((quad ^ bsw) << 3)];
            const short8 bl1 = *(const short8*)&s_wl[(brow << 6) + (((4 | quad) ^ bsw) << 3)];
            acc[ct] = MFMA16(ah0, bh0, acc[ct]);
            acc[ct] = MFMA16(ah1, bh1, acc[ct]);
            acc[ct] = MFMA16(al0, bh0, acc[ct]);
            acc[ct] = MFMA16(al1, bh1, acc[ct]);
            acc[ct] = MFMA16(ah0, bl0, acc[ct]);
            acc[ct] = MFMA16(ah1, bl1, acc[ct]);
        }
    }

    // ---- epilogue: C/D col = lane&15, row = quad*4+r (within wave's 16 rows)
    const int h = o0 >> 6;
    if (z == 0) {
        #pragma unroll
        for (int r = 0; r < 4; ++r) {
            const int rg = r0 + (w << 4) + (quad << 2) + r;
            const int bb = rg >> 10, n = rg & 1023;
            float* orow = qout + ((size_t)(bb * HH + h) * NN + n) * CC;
            #pragma unroll
            for (int ct = 0; ct < 4; ++ct)
                orow[(ct << 4) + l15] = acc[ct][r] + bias[o0 + (ct << 4) + l15];
        }
    } else if (z == 1) {
        #pragma unroll
        for (int r = 0; r < 4; ++r) {
            const int rg = r0 + (w << 4) + (quad << 2) + r;
            const int bb = rg >> 10, m = rg & 1023;
            const size_t base = ((size_t)(bb * HH + h) << 16) + ((size_t)m << 6);
            const int msw = m & 7;
            #pragma unroll
            for (int ct = 0; ct < 4; ++ct) {
                const int c = (ct << 4) + l15;
                const float o = acc[ct][r] + bias[o0 + c];
                const unsigned short hh = f2bf(o);
                const unsigned short ll = f2bf(o - bf2f(hh));
                const size_t addr = base + ((((c >> 3) ^ msw) << 3) + (c & 7));
                khi[addr] = hh;
                klo[addr] = ll;
            }
        }
    } else {
        __syncthreads();                     // all frag reads done before bounce reuse
        unsigned short* s_t = s_xh;          // [c=64][64] mirrored vT tile (swizzled)
        #pragma unroll
        for (int r = 0; r < 4; ++r) {
            const int m_l = (w << 4) + (quad << 2) + r;
            #pragma unroll
            for (int ct = 0; ct < 4; ++ct) {
                const int c = (ct << 4) + l15;
                const float o = acc[ct][r] + bias[o0 + c];
                s_t[(c << 6) + ((((m_l >> 3) ^ (c & 7)) << 3) + (m_l & 7))] = f2bf(o);
            }
        }
        __syncthreads();
        const int bb = r0 >> 10, m0 = r0 & 1023;
        const size_t bhb = ((size_t)(bb * HH + h) << 16);
        const int c = t >> 2, part = t & 3;
        const short8 v0 = *(const short8*)&s_t[(c << 6) + (part << 4)];
        const short8 v1 = *(const short8*)&s_t[(c << 6) + (part << 4) + 8];
        unsigned short* dst = vTg + bhb + ((size_t)c << 10) + m0 + (part << 4);
        *(short8*)&dst[0] = v0;
        *(short8*)&dst[8] = v1;
    }
}

// ---------------------------------------------------------------------------
// Kernel 2: fused subspace attention, MFMA bf16.
// R6 deltas vs R3 (both cache-friendly, NO nt stores):
//   (a) full-line attn store pattern: each 8-lane sn-group's store instruction
//       now covers 128 B contiguous (lane mg -> [m0+mg*4) / [m0+32+mg*4)),
//       instead of the old 16B-interleaved half-line pair -> no L2 RFO /
//       partial-line writeback.  Stash LDS layout unchanged (writer remap only).
//   (b) bh-major block swizzle: blk = ntile*16 + bh => blk%8 = bh%8, so all
//       128 blocks of a bh land on one XCD; its 384 KB K/V stays L2-resident.
// ---------------------------------------------------------------------------
__global__ __launch_bounds__(256, 3) void attn_kernel(
    const float* __restrict__ qws,
    const unsigned short* __restrict__ khi_g, const unsigned short* __restrict__ klo_g,
    const unsigned short* __restrict__ vT_g,
    const float* __restrict__ qsub, const float* __restrict__ ksub,
    float* __restrict__ out_hidden, float* __restrict__ out_attn)
{
    // smem layout (50048 B total, aliased regions):
    //   [0,16384)      region0: B: kh[64][64]+kl[64][64]; C: vT[64][64]+stash[32][72]
    //   [16384,49280)  region1: s_S [8][1028] fp32; phase-A qh/ql live here first
    //   [49280,49536)  s_qs, s_inv
    __shared__ __align__(16) unsigned char smem[50048];
    unsigned short* s_kh = (unsigned short*)smem;
    unsigned short* s_kl = s_kh + 4096;
    unsigned short* s_vT = s_kh;            // phase C alias
    unsigned short* s_at = s_kh + 4096;     // phase C stash [32][72]
    float* s_S  = (float*)(smem + 16384);   // stride 1028 floats
    unsigned short* s_qh = (unsigned short*)(smem + 16384);
    unsigned short* s_ql = s_qh + 16 * 72;
    float* s_qs  = (float*)(smem + 49280);  // qsub * 0.125 * log2e, [s][n]
    float* s_inv = (float*)(smem + 49408);  // -log2(denom), [s][n]

    const int t     = threadIdx.x;
    const int blk   = blockIdx.x;           // 2048 = ntile*16 + bh  (bh-major swizzle)
    const int bh    = blk & 15;
    const int ntile = blk >> 4;
    const int b     = bh >> 3;
    const int h     = bh & 7;
    const int n0    = ntile * 8;

    const int lane = t & 63;
    const int w    = t >> 6;                // wave 0..3
    const int l15  = lane & 15;
    const int quad = lane >> 4;

    // ---- Phase A: q tile -> split bf16 LDS; qs scales ----
    if (t < 128) {
        const int row = t >> 4, c4 = t & 15;
        const float4 qv = *(const float4*)&qws[((size_t)bh * NN + n0 + row) * CC + c4 * 4];
        const unsigned short h0 = f2bf(qv.x), h1 = f2bf(qv.y), h2 = f2bf(qv.z), h3 = f2bf(qv.w);
        short4v hh = { (short)h0, (short)h1, (short)h2, (short)h3 };
        short4v ll = { (short)f2bf(qv.x - bf2f(h0)), (short)f2bf(qv.y - bf2f(h1)),
                       (short)f2bf(qv.z - bf2f(h2)), (short)f2bf(qv.w - bf2f(h3)) };
        *(short4v*)&s_qh[row * 72 + c4 * 4] = hh;
        *(short4v*)&s_ql[row * 72 + c4 * 4] = ll;
    }
    for (int i = 576 + t; i < 1152; i += 256) { s_qh[i] = 0; s_ql[i] = 0; }   // zero pad rows 8..15
    if (t < 32) s_qs[t] = qsub[((size_t)b * SS + (t >> 3)) * NN + n0 + (t & 7)]
                        * (0.125f * 1.44269504088896f);
    __syncthreads();

    // per-wave q fragments (A-layout: row = lane&15, k = quad*8+j), reused all m-tiles.
    const short8 qh0 = *(const short8*)&s_qh[l15 * 72 + 0  + quad * 8];
    const short8 qh1 = *(const short8*)&s_qh[l15 * 72 + 32 + quad * 8];
    const short8 ql0 = *(const short8*)&s_ql[l15 * 72 + 0  + quad * 8];
    const short8 ql1 = *(const short8*)&s_ql[l15 * 72 + 32 + quad * 8];

    const unsigned short* kh_g = khi_g + ((size_t)bh << 16);
    const unsigned short* kl_g = klo_g + ((size_t)bh << 16);

    // ---- Phase B: S = q@k^T (split bf16), S->LDS fp32 ----
    #pragma unroll 1
    for (int mt = 0; mt < 16; ++mt) {
        const int m0 = mt << 6;
        #pragma unroll
        for (int i = 0; i < 4; ++i) {           // stage 16 KB (khi+klo tile) via gll width-16
            const int idx = w * 4 + i;          // 0..15
            const int j   = ((idx & 7) << 6) + lane;           // chunk id within 8 KB half
            const unsigned short* src = ((idx < 8) ? kh_g : kl_g)
                                      + ((size_t)(m0 + (j >> 3)) << 6) + ((j & 7) << 3);
            gll16(src, s_kh + (idx << 9));
        }
        __syncthreads();                         // drains gll (vmcnt0); no stores in flight in B

        const int krow = (w << 4) + l15;
        const int sw   = krow & 7;
        const short8 kh0f = *(const short8*)&s_kh[(krow << 6) + ((quad ^ sw) << 3)];
        const short8 kh1f = *(const short8*)&s_kh[(krow << 6) + (((4 | quad) ^ sw) << 3)];
        const short8 kl0f = *(const short8*)&s_kl[(krow << 6) + ((quad ^ sw) << 3)];
        const short8 kl1f = *(const short8*)&s_kl[(krow << 6) + (((4 | quad) ^ sw) << 3)];
        f32x4 acc = {0.f, 0.f, 0.f, 0.f};
        acc = MFMA16(qh0, kh0f, acc);
        acc = MFMA16(qh1, kh1f, acc);
        acc = MFMA16(ql0, kh0f, acc);
        acc = MFMA16(ql1, kh1f, acc);
        acc = MFMA16(qh0, kl0f, acc);
        acc = MFMA16(qh1, kl1f, acc);

        if (quad < 2) {                          // C/D: col=lane&15 (m), row=quad*4+r (n)
            const int mglob = m0 + krow;
            #pragma unroll
            for (int r = 0; r < 4; ++r)
                s_S[(quad * 4 + r) * 1028 + mglob] = acc[r];
        }
        __syncthreads();
    }

    // ---- Phase C setup + pre-issue tile-0 V staging (covered by the sweep) ----
    const unsigned short* vg = vT_g + ((size_t)bh << 16);
    auto stage_v = [&](int m0v) {
        #pragma unroll
        for (int i = 0; i < 2; ++i) {
            const int idx = (w << 1) + i;        // 0..7
            const int j   = (idx << 6) + lane;
            const unsigned short* src = vg + ((size_t)(j >> 3) << 10) + m0v + ((j & 7) << 3);
            gll16(src, s_vT + (idx << 9));
        }
    };
    stage_v(0);

    // ---- denominator sweep: all 256 lanes, bank-rotated s_S reads ----
    {
        const int sn = t >> 3, mg = t & 7;
        const int sD = sn >> 3, nD = sn & 7;
        const float qsD = s_qs[sn];
        const float* ksD  = ksub + ((size_t)b * SS + sD) * MM + (mg << 7);
        const float* Srow = s_S + nD * 1028 + (mg << 7);
        float d = 0.f;
        #pragma unroll 4
        for (int ii = 0; ii < 32; ++ii) {
            const int i = (ii + mg) & 31;        // rotate start: spreads banks across mg
            const f32x4  Sv = *(const f32x4*)&Srow[i << 2];
            const float4 kv = *(const float4*)&ksD[i << 2];
            d += fexp2(Sv[0] * qsD * kv.x) + fexp2(Sv[1] * qsD * kv.y)
               + fexp2(Sv[2] * qsD * kv.z) + fexp2(Sv[3] * qsD * kv.w);
        }
        d += __shfl_xor(d, 1); d += __shfl_xor(d, 2); d += __shfl_xor(d, 4);
        if (mg == 0) s_inv[sn] = -__builtin_amdgcn_logf(d);   // -log2(denom)
    }
    __syncthreads();                             // publishes s_inv; drains tile-0 gll

    // ---- Phase C: exp + attn store + stash; AV via MFMA ----
    const int sn = t >> 3, mg = t & 7;
    const int sC = sn >> 3, nC = sn & 7;
    const float linvC = s_inv[sn];
    const float qsC   = s_qs[sn];
    const float* ksC = ksub + ((size_t)b * SS + sC) * MM;
    float* attnC = out_attn + (((size_t)(bh * SS + sC)) * NN + n0 + nC) * MM;
    const int Mt = w >> 1, nsel = w & 1;
    f32x4 av0 = {0.f, 0.f, 0.f, 0.f}, av1 = {0.f, 0.f, 0.f, 0.f};

    #pragma unroll 1
    for (int mt = 0; mt < 16; ++mt) {
        const int m0 = mt << 6;
        {   // exp2(arg - log2(denom)): full-line fp32 store + bf16 stash
            const int c0 = m0 + (mg << 2);       // 8-lane group covers [m0, m0+32)
            const int c1 = m0 + 32 + (mg << 2);  // and [m0+32, m0+64) -> 128 B/instr
            const f32x4 S0 = *(const f32x4*)&s_S[nC * 1028 + c0];
            const f32x4 S1 = *(const f32x4*)&s_S[nC * 1028 + c1];
            const float4 k0 = *(const float4*)&ksC[c0];
            const float4 k1 = *(const float4*)&ksC[c1];
            float4 e0, e1;
            e0.x = fexp2(fmaf(S0[0] * qsC, k0.x, linvC));
            e0.y = fexp2(fmaf(S0[1] * qsC, k0.y, linvC));
            e0.z = fexp2(fmaf(S0[2] * qsC, k0.z, linvC));
            e0.w = fexp2(fmaf(S0[3] * qsC, k0.w, linvC));
            e1.x = fexp2(fmaf(S1[0] * qsC, k1.x, linvC));
            e1.y = fexp2(fmaf(S1[1] * qsC, k1.y, linvC));
            e1.z = fexp2(fmaf(S1[2] * qsC, k1.z, linvC));
            e1.w = fexp2(fmaf(S1[3] * qsC, k1.w, linvC));
            *(float4*)&attnC[c0] = e0;
            *(float4*)&attnC[c1] = e1;
            short4v p0 = { (short)f2bf(e0.x), (short)f2bf(e0.y),
                           (short)f2bf(e0.z), (short)f2bf(e0.w) };
            short4v p1 = { (short)f2bf(e1.x), (short)f2bf(e1.y),
                           (short)f2bf(e1.z), (short)f2bf(e1.w) };
            *(short4v*)&s_at[sn * 72 + (mg << 2)]      = p0;   // stash layout unchanged:
            *(short4v*)&s_at[sn * 72 + 32 + (mg << 2)] = p1;   // value m-local p at [sn][p]
        }
        // counted wait: glls (oldest) must retire; the attn stores stay in flight
        asm volatile("s_waitcnt vmcnt(2) lgkmcnt(0)" ::: "memory");
        __builtin_amdgcn_sched_barrier(0);
        __builtin_amdgcn_s_barrier();
        __builtin_amdgcn_sched_barrier(0);

        // AV: D[32 sn][64 c] over K=64 this tile; wave: M-tile Mt, N-tiles {nsel, nsel+2}
        #pragma unroll
        for (int Ks = 0; Ks < 2; ++Ks) {
            const int c0r = (nsel << 4) + l15, c1r = ((nsel + 2) << 4) + l15;
            const int swv = l15 & 7;
            const short8 a   = *(const short8*)&s_at[((Mt << 4) + l15) * 72 + (Ks << 5) + (quad << 3)];
            const short8 vb0 = *(const short8*)&s_vT[(c0r << 6) + ((((Ks << 2) | quad) ^ swv) << 3)];
            const short8 vb1 = *(const short8*)&s_vT[(c1r << 6) + ((((Ks << 2) | quad) ^ swv) << 3)];
            av0 = MFMA16(a, vb0, av0);
            av1 = MFMA16(a, vb1, av1);
        }
        asm volatile("s_waitcnt lgkmcnt(0)" ::: "memory");
        __builtin_amdgcn_sched_barrier(0);
        __builtin_amdgcn_s_barrier();
        __builtin_amdgcn_sched_barrier(0);
        if (mt < 15) stage_v(m0 + 64);           // next tile; pinned after barrier
        __builtin_amdgcn_sched_barrier(0);
    }

    // ---- hidden store: lane holds rows Mt*16+quad*4+r, cols Nt*16+l15 ----
    #pragma unroll
    for (int r = 0; r < 4; ++r) {
        const int snr = Mt * 16 + quad * 4 + r;
        const int s = snr >> 3, n = snr & 7;
        float* orow = out_hidden + (((size_t)b * SS + s) * NN + n0 + n) * DMODEL + h * CC;
        orow[nsel * 16 + l15]       = av0[r];
        orow[(nsel + 2) * 16 + l15] = av1[r];
    }
}

extern "C" void kernel_launch(void* const* d_in, const int* in_sizes, int n_in,
                              void* d_out, int out_size, void* d_ws, size_t ws_size,
                              hipStream_t stream) {
    const float* xq   = (const float*)d_in[0];
    const float* xk   = (const float*)d_in[1];
    const float* xv   = (const float*)d_in[2];
    const float* qsub = (const float*)d_in[3];
    const float* ksub = (const float*)d_in[4];
    const float* Wq   = (const float*)d_in[5];
    const float* bq   = (const float*)d_in[6];
    const float* Wk   = (const float*)d_in[7];
    const float* bk   = (const float*)d_in[8];
    const float* Wv   = (const float*)d_in[9];
    const float* bv   = (const float*)d_in[10];

    float* ws = (float*)d_ws;
    // ws layout: q fp32 (4 MB) | khi bf16 (2 MB) | klo bf16 (2 MB) | vT bf16 (2 MB)
    float* qf = ws;
    unsigned short* khi = (unsigned short*)(ws + 1048576);
    unsigned short* klo = khi + 1048576;
    unsigned short* vTg = klo + 1048576;

    float* out_hidden = (float*)d_out;              // (B,S,N,512)
    float* out_attn   = out_hidden + (size_t)BB * SS * NN * DMODEL;  // (B,H,S,N,M)

    proj_kernel<<<dim3(8, 32, 3), 256, 0, stream>>>(xq, xk, xv, Wq, Wk, Wv, bq, bk, bv,
                                                    qf, khi, klo, vTg);
    attn_kernel<<<dim3(2048), 256, 0, stream>>>(qf, khi, klo, vTg,
                                                qsub, ksub, out_hidden, out_attn);
}